// Round 15
// baseline (286.941 us; speedup 1.0000x reference)
//
#include <hip/hip_runtime.h>
#include <cstdint>
#include <cstddef>

#define N_  8
#define C_  256
#define HW_ 1024
#define CL_ 16
#define SZ_ (N_*C_*HW_)   // 2,097,152 elements per tensor
#define WSCALE_ 4096.0f   // 2^12 exact; folded into A, cancels in L2-norm

typedef __attribute__((ext_vector_type(8))) _Float16 half8;
typedef __attribute__((ext_vector_type(4))) float f32x4;

static __device__ __forceinline__ float tanh_fast(float x){
  x = fminf(fmaxf(x, -15.f), 15.f);
  float e = __expf(2.f * x);
  return (e - 1.f) / (e + 1.f);
}

static __device__ __forceinline__ unsigned short f2h(float x){
  _Float16 h = (_Float16)x;
  return *(unsigned short*)&h;
}

// combine 16 online-softmax partials -> (m, 1/sumexp)
static __device__ __forceinline__ void combine16(
    const float* __restrict__ mpart, const float* __restrict__ spart,
    int base, float& m, float& rl)
{
  m = -1e30f;
  #pragma unroll
  for (int k = 0; k < 16; ++k) m = fmaxf(m, mpart[base * 16 + k]);
  float s = 0.f;
  #pragma unroll
  for (int k = 0; k < 16; ++k) s += spart[base * 16 + k] * __expf(mpart[base * 16 + k] - m);
  rl = 1.f / s;
}

#define GLD16(g, l) __builtin_amdgcn_global_load_lds( \
    (const __attribute__((address_space(1))) void*)(g), \
    (__attribute__((address_space(3))) void*)(l), 16, 0, 0)

#define WAITV(N) asm volatile("s_waitcnt vmcnt(" #N ")" ::: "memory")

// K1 (once): sa-dot on original fp32 inputs + fp16 mirror write.
__global__ __launch_bounds__(256) void k_sa_dot(
    const float* __restrict__ fp1, const float* __restrict__ fp2,
    const float* __restrict__ cw1, const float* __restrict__ cw2,
    const float* __restrict__ pw1, const float* __restrict__ pw2,
    float* __restrict__ cval, float* __restrict__ pdot,
    float* __restrict__ mpart, float* __restrict__ spart,
    _Float16* __restrict__ fh1, _Float16* __restrict__ fh2)
{
  const int bid = blockIdx.x;
  const int n = bid & 7, r = bid >> 3;
  const int side = r >> 4, hw0 = (r & 15) * 64;
  const int t = threadIdx.x, hwl = t & 63, cg = t >> 6;
  const float* __restrict__ pw = side ? pw2 : pw1;
  const float* __restrict__ cw = side ? cw2 : cw1;
  const float* __restrict__ f  = (side ? fp2 : fp1) + (size_t)n * C_ * HW_ + hw0 + hwl;
  _Float16* __restrict__ fh = (side ? fh2 : fh1) + (size_t)n * C_ * HW_ + hw0 + hwl;
  const int cb = __builtin_amdgcn_readfirstlane(cg * 64);

  float acc[17];
  #pragma unroll
  for (int l = 0; l < 17; ++l) acc[l] = 0.f;

  for (int cc = 0; cc < 64; ++cc){
    const int c = cb + cc;
    const float v = f[(size_t)c * HW_];
    fh[(size_t)c * HW_] = (_Float16)v;
    acc[16] += v * cw[c];
    #pragma unroll
    for (int l = 0; l < 16; ++l) acc[l] += v * pw[l * C_ + c];
  }

  __shared__ float red[17][4][64];
  #pragma unroll
  for (int l = 0; l < 17; ++l) red[l][cg][hwl] = acc[l];
  __syncthreads();

  if (t < 64){
    const int base = n * 2 + side;
    float xc = 0.f;
    #pragma unroll
    for (int l = 0; l < 17; ++l){
      const float s = red[l][0][t] + red[l][1][t] + red[l][2][t] + red[l][3][t];
      if (l < 16) pdot[((size_t)base * CL_ + l) * HW_ + hw0 + t] = s;
      else      { cval[(size_t)base * HW_ + hw0 + t] = s; xc = s; }
    }
    float mb = xc;
    #pragma unroll
    for (int off = 32; off; off >>= 1) mb = fmaxf(mb, __shfl_xor(mb, off));
    float e = __expf(xc - mb);
    #pragma unroll
    for (int off = 32; off; off >>= 1) e += __shfl_xor(e, off);
    if (t == 0){
      mpart[base * 16 + (hw0 >> 6)] = mb;
      spart[base * 16 + (hw0 >> 6)] = e;
    }
  }
}

// K2: corr -> scaled-w-folded fp16 A / At (XCD-affine n = bid & 7)
__global__ __launch_bounds__(256) void k_corr(
    const float* __restrict__ cval, const float* __restrict__ pdot,
    const float* __restrict__ pb1, const float* __restrict__ pb2,
    const float* __restrict__ mpart, const float* __restrict__ spart,
    unsigned short* __restrict__ Abf, unsigned short* __restrict__ Atbf)
{
  const int bid = blockIdx.x;
  const int n = bid & 7, r4i = bid >> 3;
  const int i0 = (r4i >> 4) * 64, j0 = (r4i & 15) * 64;
  const int b1 = n * 2, b2 = n * 2 + 1;
  __align__(16) __shared__ float s2[CL_][64];
  __align__(16) __shared__ float s1[CL_][64];
  __shared__ unsigned short at_s[64][68];
  const int t = threadIdx.x;
  const int lr = t >> 4, lc = (t & 15) * 4;

  float m1, rl1, m2, rl2;
  combine16(mpart, spart, b1, m1, rl1);
  combine16(mpart, spart, b2, m2, rl2);

  {
    const float bias2 = pb2[lr];
    const float4 c2 = *(const float4*)&cval[(size_t)b2 * HW_ + i0 + lc];
    const float4 p2 = *(const float4*)&pdot[((size_t)b2 * CL_ + lr) * HW_ + i0 + lc];
    s2[lr][lc + 0] = __expf(c2.x - m2) * rl2 * p2.x + bias2;
    s2[lr][lc + 1] = __expf(c2.y - m2) * rl2 * p2.y + bias2;
    s2[lr][lc + 2] = __expf(c2.z - m2) * rl2 * p2.z + bias2;
    s2[lr][lc + 3] = __expf(c2.w - m2) * rl2 * p2.w + bias2;

    const float bias1 = pb1[lr];
    const float4 c1 = *(const float4*)&cval[(size_t)b1 * HW_ + j0 + lc];
    const float4 p1 = *(const float4*)&pdot[((size_t)b1 * CL_ + lr) * HW_ + j0 + lc];
    s1[lr][lc + 0] = __expf(c1.x - m1) * rl1 * p1.x + bias1;
    s1[lr][lc + 1] = __expf(c1.y - m1) * rl1 * p1.y + bias1;
    s1[lr][lc + 2] = __expf(c1.z - m1) * rl1 * p1.z + bias1;
    s1[lr][lc + 3] = __expf(c1.w - m1) * rl1 * p1.w + bias1;
  }
  __syncthreads();

  const int ti = t >> 4, tj = t & 15;
  float acc[4][4];
  #pragma unroll
  for (int a = 0; a < 4; ++a)
    #pragma unroll
    for (int b = 0; b < 4; ++b) acc[a][b] = 0.f;

  #pragma unroll
  for (int l = 0; l < CL_; ++l){
    const float4 a4 = *(const float4*)&s2[l][ti * 4];
    const float4 b4 = *(const float4*)&s1[l][tj * 4];
    const float av[4] = {a4.x, a4.y, a4.z, a4.w};
    const float bv[4] = {b4.x, b4.y, b4.z, b4.w};
    #pragma unroll
    for (int a = 0; a < 4; ++a)
      #pragma unroll
      for (int b = 0; b < 4; ++b) acc[a][b] += av[a] * bv[b];
  }

  float tf[4][4];
  #pragma unroll
  for (int a = 0; a < 4; ++a)
    #pragma unroll
    for (int b = 0; b < 4; ++b) tf[a][b] = tanh_fast(acc[a][b]);

  float w1j[4], w2i[4];
  #pragma unroll
  for (int b = 0; b < 4; ++b)
    w1j[b] = WSCALE_ * __expf(cval[(size_t)b1 * HW_ + j0 + tj * 4 + b] - m1) * rl1;
  #pragma unroll
  for (int a = 0; a < 4; ++a)
    w2i[a] = WSCALE_ * __expf(cval[(size_t)b2 * HW_ + i0 + ti * 4 + a] - m2) * rl2;

  unsigned short* __restrict__ An  = Abf  + ((size_t)n << 20);
  unsigned short* __restrict__ Atn = Atbf + ((size_t)n << 20);
  #pragma unroll
  for (int a = 0; a < 4; ++a){
    ushort4 va;
    va.x = f2h(tf[a][0] * w1j[0]); va.y = f2h(tf[a][1] * w1j[1]);
    va.z = f2h(tf[a][2] * w1j[2]); va.w = f2h(tf[a][3] * w1j[3]);
    *(ushort4*)&An[(size_t)(i0 + ti * 4 + a) * HW_ + j0 + tj * 4] = va;
  }
  #pragma unroll
  for (int b = 0; b < 4; ++b){
    ushort4 vb;
    vb.x = f2h(tf[0][b] * w2i[0]); vb.y = f2h(tf[1][b] * w2i[1]);
    vb.z = f2h(tf[2][b] * w2i[2]); vb.w = f2h(tf[3][b] * w2i[3]);
    *(ushort4*)&at_s[tj * 4 + b][ti * 4] = vb;
  }
  __syncthreads();
  #pragma unroll
  for (int rep = 0; rep < 2; ++rep){
    const int idx = t + rep * 256;
    const int r = idx >> 3, q = (idx & 7) * 8;
    const ushort4 lo = *(const ushort4*)&at_s[r][q];
    const ushort4 hi = *(const ushort4*)&at_s[r][q + 4];
    *(ushort4*)&Atn[(size_t)(j0 + r) * HW_ + i0 + q] = lo;
    *(ushort4*)&Atn[(size_t)(j0 + r) * HW_ + i0 + q + 4] = hi;
  }
}

// K3a: split-K MFMA GEMM main loop -> fp32 partials.
// Grid 512 = (n, g, i-tile, kh): 2 blocks/CU co-resident -> cross-block latency overlap.
__global__ __launch_bounds__(512, 4) void k_gemm_split(
    const _Float16* __restrict__ fhc1, const _Float16* __restrict__ fhc2,
    const unsigned short* __restrict__ Abf, const unsigned short* __restrict__ Atbf,
    float* __restrict__ ppart)
{
  const int bid = blockIdx.x;
  const int n = bid & 7;
  const int b2 = bid >> 3;           // 0..63
  const int kh = b2 & 1;
  const int it = (b2 >> 1) & 15;
  const int g  = b2 >> 5;
  const int i0 = it * 64;
  const int kbase = kh * 512;

  const unsigned short* __restrict__ X =
      (const unsigned short*)((g ? fhc2 : fhc1) + (size_t)n * C_ * HW_);
  const unsigned short* __restrict__ B = (g ? Atbf : Abf) + ((size_t)n << 20);

  __shared__ __align__(16) unsigned char pool[61440];  // 60 KB: 2 blocks/CU
  // Xs[buf] at buf*16384 (3x16KB); Bs[buf] at 49152 + buf*4096 (3x4KB)

  const int t = threadIdx.x, w = t >> 6, l = t & 63;
  const int wr = w >> 1, wc = w & 1;

  f32x4 acc[4][2];
  #pragma unroll
  for (int fm = 0; fm < 4; ++fm)
    #pragma unroll
    for (int fn = 0; fn < 2; ++fn)
      acc[fm][fn] = (f32x4){0.f, 0.f, 0.f, 0.f};

  auto stage = [&](int buf, int k0){
    unsigned short* Xsb = (unsigned short*)(pool + buf * 16384);
    #pragma unroll
    for (int s = 0; s < 2; ++s){
      const int q = (w * 2 + s) * 64 + l;
      const int row = q >> 2;
      const int kc = (q & 3) ^ (row & 3);
      GLD16(X + (size_t)row * HW_ + k0 + kc * 8, &Xsb[(w * 2 + s) * 512]);
    }
    if (w < 4){
      unsigned short* Bsb = (unsigned short*)(pool + 49152 + buf * 4096);
      const int q = w * 64 + l;
      const int row = q >> 2;
      const int kc = (q & 3) ^ (row & 3);
      GLD16(B + (size_t)(i0 + row) * HW_ + k0 + kc * 8, &Bsb[w * 512]);
    }
  };

  stage(0, kbase);
  stage(1, kbase + 32);
  stage(2, kbase + 64);

  int cur = 0;
  for (int kt = 0; kt < 16; ++kt){
    const int rem = (15 - kt) < 2 ? (15 - kt) : 2;
    if (w < 4){
      if (rem == 2)      WAITV(6);
      else if (rem == 1) WAITV(3);
      else               WAITV(0);
    } else {
      if (rem == 2)      WAITV(4);
      else if (rem == 1) WAITV(2);
      else               WAITV(0);
    }
    __builtin_amdgcn_sched_barrier(0);
    __builtin_amdgcn_s_barrier();

    const unsigned short* Xsb = (const unsigned short*)(pool + cur * 16384);
    const unsigned short* Bsb = (const unsigned short*)(pool + 49152 + cur * 4096);
    half8 a[4], bb[2];
    #pragma unroll
    for (int fm = 0; fm < 4; ++fm){
      const int row = wr * 64 + fm * 16 + (l & 15);
      const int kc = (l >> 4) ^ (row & 3);
      a[fm] = *(const half8*)&Xsb[row * 32 + kc * 8];
    }
    #pragma unroll
    for (int fn = 0; fn < 2; ++fn){
      const int row = wc * 32 + fn * 16 + (l & 15);
      const int kc = (l >> 4) ^ (row & 3);
      bb[fn] = *(const half8*)&Bsb[row * 32 + kc * 8];
    }
    #pragma unroll
    for (int fm = 0; fm < 4; ++fm)
      #pragma unroll
      for (int fn = 0; fn < 2; ++fn)
        acc[fm][fn] = __builtin_amdgcn_mfma_f32_16x16x32_f16(a[fm], bb[fn], acc[fm][fn], 0, 0, 0);

    asm volatile("s_waitcnt lgkmcnt(0)" ::: "memory");
    __builtin_amdgcn_sched_barrier(0);
    __builtin_amdgcn_s_barrier();
    __builtin_amdgcn_sched_barrier(0);

    if (kt < 13) stage(cur, kbase + (kt + 3) * 32);
    cur = (cur == 2) ? 0 : cur + 1;
  }

  // write fp32 partials: ppart[pair][kh][c][i]
  float* __restrict__ pp = ppart + (((size_t)(n * 2 + g) * 2 + kh) * C_) * HW_;
  const int rbase = (l >> 4) * 4, col = l & 15;
  #pragma unroll
  for (int fm = 0; fm < 4; ++fm)
    #pragma unroll
    for (int fn = 0; fn < 2; ++fn){
      const size_t base = (size_t)(wr * 64 + fm * 16 + rbase) * HW_ + i0 + wc * 32 + fn * 16 + col;
      #pragma unroll
      for (int r = 0; r < 4; ++r)
        pp[base + (size_t)r * HW_] = acc[fm][fn][r];
    }
}

// K3b: finish = sum split-K partials + L2-norm + resid/ReLU + fp16 mirror +
//       next-iter sa-dot (or h output at last).
__global__ __launch_bounds__(512, 4) void k_finish(
    const float* __restrict__ ppart,
    const float* __restrict__ fpin1, const float* __restrict__ fpin2,
    float* __restrict__ fpo1, float* __restrict__ fpo2,
    _Float16* __restrict__ fhn1, _Float16* __restrict__ fhn2,
    const float* __restrict__ pw1, const float* __restrict__ pw2,
    const float* __restrict__ cw1, const float* __restrict__ cw2,
    float* __restrict__ cval, float* __restrict__ pdot,
    float* __restrict__ mpart, float* __restrict__ spart,
    float* __restrict__ out, int last)
{
  const int bid = blockIdx.x;
  const int n = bid & 7, r2 = bid >> 3;
  const int g = r2 >> 4, i0 = (r2 & 15) * 64;

  __shared__ __align__(16) unsigned char pool[40960];
  float* pwT   = (float*)pool;             // [256][20] = 20480 B
  float* redp  = (float*)(pool + 20480);   // [4][2][2][17][16] = 17408 B
  float* ssred = (float*)(pool + 37888);   // [4][64] = 1024 B
  float* rinvp = (float*)(pool + 38912);   // [64] = 256 B

  const int t = threadIdx.x, w = t >> 6, l = t & 63;
  const int wr = w >> 1, wc = w & 1;
  const int rbase = (l >> 4) * 4, col = l & 15;

  const float* __restrict__ pp0 = ppart + (((size_t)(n * 2 + g) * 2 + 0) * C_) * HW_;
  const float* __restrict__ pp1 = pp0 + (size_t)C_ * HW_;

  f32x4 acc[4][2];
  #pragma unroll
  for (int fm = 0; fm < 4; ++fm)
    #pragma unroll
    for (int fn = 0; fn < 2; ++fn){
      const size_t base = (size_t)(wr * 64 + fm * 16 + rbase) * HW_ + i0 + wc * 32 + fn * 16 + col;
      #pragma unroll
      for (int r = 0; r < 4; ++r)
        acc[fm][fn][r] = pp0[base + (size_t)r * HW_] + pp1[base + (size_t)r * HW_];
    }

  float ss0 = 0.f, ss1 = 0.f;
  #pragma unroll
  for (int fm = 0; fm < 4; ++fm)
    #pragma unroll
    for (int r = 0; r < 4; ++r){
      ss0 += acc[fm][0][r] * acc[fm][0][r];
      ss1 += acc[fm][1][r] * acc[fm][1][r];
    }
  ss0 += __shfl_xor(ss0, 16); ss0 += __shfl_xor(ss0, 32);
  ss1 += __shfl_xor(ss1, 16); ss1 += __shfl_xor(ss1, 32);
  if (l < 16){
    ssred[wr * 64 + wc * 32 + l]      = ss0;
    ssred[wr * 64 + wc * 32 + 16 + l] = ss1;
  }

  if (!last){
    const float* __restrict__ pw = g ? pw2 : pw1;
    const float* __restrict__ cw = g ? cw2 : cw1;
    {
      const int idx = t * 8;
      const int lq = idx >> 8, c = idx & 255;
      const float4 p0 = *(const float4*)&pw[lq * C_ + c];
      const float4 p1 = *(const float4*)&pw[lq * C_ + c + 4];
      pwT[(c + 0) * 20 + lq] = p0.x; pwT[(c + 1) * 20 + lq] = p0.y;
      pwT[(c + 2) * 20 + lq] = p0.z; pwT[(c + 3) * 20 + lq] = p0.w;
      pwT[(c + 4) * 20 + lq] = p1.x; pwT[(c + 5) * 20 + lq] = p1.y;
      pwT[(c + 6) * 20 + lq] = p1.z; pwT[(c + 7) * 20 + lq] = p1.w;
    }
    if (t < 32){
      const float4 c0 = *(const float4*)&cw[t * 8];
      const float4 c1 = *(const float4*)&cw[t * 8 + 4];
      pwT[(t * 8 + 0) * 20 + 16] = c0.x; pwT[(t * 8 + 1) * 20 + 16] = c0.y;
      pwT[(t * 8 + 2) * 20 + 16] = c0.z; pwT[(t * 8 + 3) * 20 + 16] = c0.w;
      pwT[(t * 8 + 4) * 20 + 16] = c1.x; pwT[(t * 8 + 5) * 20 + 16] = c1.y;
      pwT[(t * 8 + 6) * 20 + 16] = c1.z; pwT[(t * 8 + 7) * 20 + 16] = c1.w;
    }
  }
  __syncthreads();
  if (t < 64){
    const float s = ssred[t] + ssred[64 + t] + ssred[128 + t] + ssred[192 + t];
    rinvp[t] = 1.f / fmaxf(sqrtf(s), 1e-12f);
  }
  __syncthreads();
  const float ri[2] = { rinvp[wc * 32 + (l & 15)], rinvp[wc * 32 + 16 + (l & 15)] };

  const float* __restrict__ fpin = (g ? fpin2 : fpin1) + (size_t)n * C_ * HW_;
  float* __restrict__ fpo  = (g ? fpo2 : fpo1) + (size_t)n * C_ * HW_;
  _Float16* __restrict__ fhn = (g ? fhn2 : fhn1) + (size_t)n * C_ * HW_;
  float* __restrict__ outp = out + (size_t)g * SZ_ + (size_t)n * C_ * HW_;
  const int baseio = n * 2 + g;

  if (!last){
    float sacc[2][17];
    #pragma unroll
    for (int fn = 0; fn < 2; ++fn)
      #pragma unroll
      for (int lq = 0; lq < 17; ++lq) sacc[fn][lq] = 0.f;

    #pragma unroll
    for (int fm = 0; fm < 4; ++fm)
      #pragma unroll
      for (int r = 0; r < 4; ++r){
        const int c = wr * 64 + fm * 16 + rbase + r;
        float prow[17];
        #pragma unroll
        for (int q4 = 0; q4 < 4; ++q4){
          const float4 pv = *(const float4*)&pwT[c * 20 + q4 * 4];
          prow[q4 * 4 + 0] = pv.x; prow[q4 * 4 + 1] = pv.y;
          prow[q4 * 4 + 2] = pv.z; prow[q4 * 4 + 3] = pv.w;
        }
        prow[16] = pwT[c * 20 + 16];
        #pragma unroll
        for (int fn = 0; fn < 2; ++fn){
          const size_t base = (size_t)c * HW_ + i0 + wc * 32 + fn * 16 + col;
          const float h = acc[fm][fn][r] * ri[fn];
          const float fv = fpin[base] + h;
          const float rv = fv > 0.f ? fv : 0.f;
          fpo[base] = rv;
          fhn[base] = (_Float16)rv;
          #pragma unroll
          for (int lq = 0; lq < 17; ++lq) sacc[fn][lq] += rv * prow[lq];
        }
      }

    #pragma unroll
    for (int fn = 0; fn < 2; ++fn)
      #pragma unroll
      for (int lq = 0; lq < 17; ++lq){
        float v = sacc[fn][lq];
        v += __shfl_xor(v, 16);
        v += __shfl_xor(v, 32);
        sacc[fn][lq] = v;
      }
    if (l < 16){
      #pragma unroll
      for (int fn = 0; fn < 2; ++fn)
        #pragma unroll
        for (int lq = 0; lq < 17; ++lq)
          redp[(((wr * 2 + wc) * 2 + fn) * 17 + lq) * 16 + l] = sacc[fn][lq];
    }
    __syncthreads();
    if (t < 64){
      const int wcx = t >> 5, fnx = (t >> 4) & 1, colx = t & 15;
      float xc = 0.f;
      #pragma unroll
      for (int lq = 0; lq < 17; ++lq){
        float s = 0.f;
        #pragma unroll
        for (int wrx = 0; wrx < 4; ++wrx)
          s += redp[(((wrx * 2 + wcx) * 2 + fnx) * 17 + lq) * 16 + colx];
        if (lq < 16) pdot[((size_t)baseio * CL_ + lq) * HW_ + i0 + t] = s;
        else       { cval[(size_t)baseio * HW_ + i0 + t] = s; xc = s; }
      }
      float mb = xc;
      #pragma unroll
      for (int off = 32; off; off >>= 1) mb = fmaxf(mb, __shfl_xor(mb, off));
      float e = __expf(xc - mb);
      #pragma unroll
      for (int off = 32; off; off >>= 1) e += __shfl_xor(e, off);
      if (t == 0){
        mpart[baseio * 16 + (i0 >> 6)] = mb;
        spart[baseio * 16 + (i0 >> 6)] = e;
      }
    }
  } else {
    #pragma unroll
    for (int fm = 0; fm < 4; ++fm)
      #pragma unroll
      for (int fn = 0; fn < 2; ++fn){
        const size_t base = (size_t)(wr * 64 + fm * 16 + rbase) * HW_ + i0 + wc * 32 + fn * 16 + col;
        #pragma unroll
        for (int r = 0; r < 4; ++r)
          outp[base + (size_t)r * HW_] = acc[fm][fn][r] * ri[fn];
      }
  }
}

// K_s: s[n,c,hw] = w * fp (fp32 state),  w = exp(cval - m) * rl
__global__ __launch_bounds__(256) void k_s_out(
    const float* __restrict__ fp1, const float* __restrict__ fp2,
    const float* __restrict__ cval,
    const float* __restrict__ mpart, const float* __restrict__ spart,
    float* __restrict__ out)
{
  const int side = blockIdx.y;
  const size_t fo = ((size_t)blockIdx.x * 256 + threadIdx.x) * 4;
  const float* __restrict__ f = side ? fp2 : fp1;
  const int n  = (int)(fo >> 18);
  const int hw = (int)(fo & (HW_ - 1));
  const int base = n * 2 + side;
  float m, rl;
  combine16(mpart, spart, base, m, rl);
  const float4 c = *(const float4*)&cval[(size_t)base * HW_ + hw];
  const float4 v = *(const float4*)&f[fo];
  float4 r;
  r.x = v.x * (__expf(c.x - m) * rl);
  r.y = v.y * (__expf(c.y - m) * rl);
  r.z = v.z * (__expf(c.z - m) * rl);
  r.w = v.w * (__expf(c.w - m) * rl);
  *(float4*)&out[(size_t)(2 + side) * SZ_ + fo] = r;
}

extern "C" void kernel_launch(void* const* d_in, const int* in_sizes, int n_in,
                              void* d_out, int out_size, void* d_ws, size_t ws_size,
                              hipStream_t stream)
{
  const float* f1  = (const float*)d_in[0];
  const float* f2  = (const float*)d_in[1];
  const float* pw1 = (const float*)d_in[2];
  const float* pb1 = (const float*)d_in[3];
  const float* pw2 = (const float*)d_in[4];
  const float* pb2 = (const float*)d_in[5];
  const float* cw1 = (const float*)d_in[6];
  const float* cw2 = (const float*)d_in[8];
  // cb1/cb2 unused: softmax is shift-invariant
  float* out = (float*)d_out;
  float* ws  = (float*)d_ws;

  float* cval  = ws;                           // 16K f32
  float* pdot  = cval + N_ * 2 * HW_;          // 256K f32
  float* mpart = pdot + N_ * 2 * CL_ * HW_;    // 512
  float* spart = mpart + 512;                  // 512
  float* fp1   = spart + 512;                  // SZ_ f32 state
  float* fp2   = fp1 + SZ_;                    // SZ_ f32 state
  _Float16* fhA1 = (_Float16*)(fp2 + SZ_);     // SZ_ fp16 mirror (ping)
  _Float16* fhA2 = fhA1 + SZ_;
  _Float16* fhB1 = fhA2 + SZ_;                 // SZ_ fp16 mirror (pong)
  _Float16* fhB2 = fhB1 + SZ_;
  unsigned short* Abf  = (unsigned short*)(fhB2 + SZ_);  // 8M fp16
  unsigned short* Atbf = Abf + ((size_t)N_ << 20);       // 8M fp16
  float* ppart = (float*)(Atbf + ((size_t)N_ << 20));    // 16x2x256x1024 f32 = 33.5 MB

  k_sa_dot<<<dim3(256), 256, 0, stream>>>(f1, f2, cw1, cw2, pw1, pw2,
                                          cval, pdot, mpart, spart, fhA1, fhA2);

  for (int it = 0; it < 5; ++it){
    const float* cur1 = (it == 0) ? f1 : fp1;
    const float* cur2 = (it == 0) ? f2 : fp2;
    const _Float16* fhc1 = (it & 1) ? fhB1 : fhA1;
    const _Float16* fhc2 = (it & 1) ? fhB2 : fhA2;
    _Float16* fhn1 = (it & 1) ? fhA1 : fhB1;
    _Float16* fhn2 = (it & 1) ? fhA2 : fhB2;

    k_corr<<<dim3(2048), 256, 0, stream>>>(cval, pdot, pb1, pb2, mpart, spart, Abf, Atbf);
    if (it == 4)
      k_s_out<<<dim3(SZ_ / 4 / 256, 2), 256, 0, stream>>>(cur1, cur2, cval, mpart, spart, out);
    k_gemm_split<<<dim3(512), 512, 0, stream>>>(fhc1, fhc2, Abf, Atbf, ppart);
    k_finish<<<dim3(256), 512, 0, stream>>>(ppart, cur1, cur2, fp1, fp2, fhn1, fhn2,
                                            pw1, pw2, cw1, cw2,
                                            cval, pdot, mpart, spart,
                                            out, (it == 4) ? 1 : 0);
  }
}

// Round 16
// 251.396 us; speedup vs baseline: 1.1414x; 1.1414x over previous
//
#include <hip/hip_runtime.h>
#include <cstdint>
#include <cstddef>

#define N_  8
#define C_  256
#define HW_ 1024
#define CL_ 16
#define SZ_ (N_*C_*HW_)   // 2,097,152 elements per tensor
#define WSCALE_ 4096.0f   // 2^12 exact; folded into A, cancels in L2-norm

typedef __attribute__((ext_vector_type(8))) _Float16 half8;
typedef __attribute__((ext_vector_type(4))) float f32x4;

static __device__ __forceinline__ float tanh_fast(float x){
  x = fminf(fmaxf(x, -15.f), 15.f);
  float e = __expf(2.f * x);
  return (e - 1.f) / (e + 1.f);
}

static __device__ __forceinline__ unsigned short f2h(float x){
  _Float16 h = (_Float16)x;
  return *(unsigned short*)&h;
}

// combine 16 online-softmax partials -> (m, 1/sumexp)
static __device__ __forceinline__ void combine16(
    const float* __restrict__ mpart, const float* __restrict__ spart,
    int base, float& m, float& rl)
{
  m = -1e30f;
  #pragma unroll
  for (int k = 0; k < 16; ++k) m = fmaxf(m, mpart[base * 16 + k]);
  float s = 0.f;
  #pragma unroll
  for (int k = 0; k < 16; ++k) s += spart[base * 16 + k] * __expf(mpart[base * 16 + k] - m);
  rl = 1.f / s;
}

#define GLD16(g, l) __builtin_amdgcn_global_load_lds( \
    (const __attribute__((address_space(1))) void*)(g), \
    (__attribute__((address_space(3))) void*)(l), 16, 0, 0)

#define WAITV(N) asm volatile("s_waitcnt vmcnt(" #N ")" ::: "memory")

// K1 (once): sa-dot on original fp32 inputs + fp16 mirror write.
__global__ __launch_bounds__(256) void k_sa_dot(
    const float* __restrict__ fp1, const float* __restrict__ fp2,
    const float* __restrict__ cw1, const float* __restrict__ cw2,
    const float* __restrict__ pw1, const float* __restrict__ pw2,
    float* __restrict__ cval, float* __restrict__ pdot,
    float* __restrict__ mpart, float* __restrict__ spart,
    _Float16* __restrict__ fh1, _Float16* __restrict__ fh2)
{
  const int bid = blockIdx.x;
  const int n = bid & 7, r = bid >> 3;
  const int side = r >> 4, hw0 = (r & 15) * 64;
  const int t = threadIdx.x, hwl = t & 63, cg = t >> 6;
  const float* __restrict__ pw = side ? pw2 : pw1;
  const float* __restrict__ cw = side ? cw2 : cw1;
  const float* __restrict__ f  = (side ? fp2 : fp1) + (size_t)n * C_ * HW_ + hw0 + hwl;
  _Float16* __restrict__ fh = (side ? fh2 : fh1) + (size_t)n * C_ * HW_ + hw0 + hwl;
  const int cb = __builtin_amdgcn_readfirstlane(cg * 64);

  float acc[17];
  #pragma unroll
  for (int l = 0; l < 17; ++l) acc[l] = 0.f;

  for (int cc = 0; cc < 64; ++cc){
    const int c = cb + cc;
    const float v = f[(size_t)c * HW_];
    fh[(size_t)c * HW_] = (_Float16)v;
    acc[16] += v * cw[c];
    #pragma unroll
    for (int l = 0; l < 16; ++l) acc[l] += v * pw[l * C_ + c];
  }

  __shared__ float red[17][4][64];
  #pragma unroll
  for (int l = 0; l < 17; ++l) red[l][cg][hwl] = acc[l];
  __syncthreads();

  if (t < 64){
    const int base = n * 2 + side;
    float xc = 0.f;
    #pragma unroll
    for (int l = 0; l < 17; ++l){
      const float s = red[l][0][t] + red[l][1][t] + red[l][2][t] + red[l][3][t];
      if (l < 16) pdot[((size_t)base * CL_ + l) * HW_ + hw0 + t] = s;
      else      { cval[(size_t)base * HW_ + hw0 + t] = s; xc = s; }
    }
    float mb = xc;
    #pragma unroll
    for (int off = 32; off; off >>= 1) mb = fmaxf(mb, __shfl_xor(mb, off));
    float e = __expf(xc - mb);
    #pragma unroll
    for (int off = 32; off; off >>= 1) e += __shfl_xor(e, off);
    if (t == 0){
      mpart[base * 16 + (hw0 >> 6)] = mb;
      spart[base * 16 + (hw0 >> 6)] = e;
    }
  }
}

// K2: corr -> scaled-w-folded fp16 A / At (XCD-affine n = bid & 7)
__global__ __launch_bounds__(256) void k_corr(
    const float* __restrict__ cval, const float* __restrict__ pdot,
    const float* __restrict__ pb1, const float* __restrict__ pb2,
    const float* __restrict__ mpart, const float* __restrict__ spart,
    unsigned short* __restrict__ Abf, unsigned short* __restrict__ Atbf)
{
  const int bid = blockIdx.x;
  const int n = bid & 7, r4i = bid >> 3;
  const int i0 = (r4i >> 4) * 64, j0 = (r4i & 15) * 64;
  const int b1 = n * 2, b2 = n * 2 + 1;
  __align__(16) __shared__ float s2[CL_][64];
  __align__(16) __shared__ float s1[CL_][64];
  __shared__ unsigned short at_s[64][68];
  const int t = threadIdx.x;
  const int lr = t >> 4, lc = (t & 15) * 4;

  float m1, rl1, m2, rl2;
  combine16(mpart, spart, b1, m1, rl1);
  combine16(mpart, spart, b2, m2, rl2);

  {
    const float bias2 = pb2[lr];
    const float4 c2 = *(const float4*)&cval[(size_t)b2 * HW_ + i0 + lc];
    const float4 p2 = *(const float4*)&pdot[((size_t)b2 * CL_ + lr) * HW_ + i0 + lc];
    s2[lr][lc + 0] = __expf(c2.x - m2) * rl2 * p2.x + bias2;
    s2[lr][lc + 1] = __expf(c2.y - m2) * rl2 * p2.y + bias2;
    s2[lr][lc + 2] = __expf(c2.z - m2) * rl2 * p2.z + bias2;
    s2[lr][lc + 3] = __expf(c2.w - m2) * rl2 * p2.w + bias2;

    const float bias1 = pb1[lr];
    const float4 c1 = *(const float4*)&cval[(size_t)b1 * HW_ + j0 + lc];
    const float4 p1 = *(const float4*)&pdot[((size_t)b1 * CL_ + lr) * HW_ + j0 + lc];
    s1[lr][lc + 0] = __expf(c1.x - m1) * rl1 * p1.x + bias1;
    s1[lr][lc + 1] = __expf(c1.y - m1) * rl1 * p1.y + bias1;
    s1[lr][lc + 2] = __expf(c1.z - m1) * rl1 * p1.z + bias1;
    s1[lr][lc + 3] = __expf(c1.w - m1) * rl1 * p1.w + bias1;
  }
  __syncthreads();

  const int ti = t >> 4, tj = t & 15;
  float acc[4][4];
  #pragma unroll
  for (int a = 0; a < 4; ++a)
    #pragma unroll
    for (int b = 0; b < 4; ++b) acc[a][b] = 0.f;

  #pragma unroll
  for (int l = 0; l < CL_; ++l){
    const float4 a4 = *(const float4*)&s2[l][ti * 4];
    const float4 b4 = *(const float4*)&s1[l][tj * 4];
    const float av[4] = {a4.x, a4.y, a4.z, a4.w};
    const float bv[4] = {b4.x, b4.y, b4.z, b4.w};
    #pragma unroll
    for (int a = 0; a < 4; ++a)
      #pragma unroll
      for (int b = 0; b < 4; ++b) acc[a][b] += av[a] * bv[b];
  }

  float tf[4][4];
  #pragma unroll
  for (int a = 0; a < 4; ++a)
    #pragma unroll
    for (int b = 0; b < 4; ++b) tf[a][b] = tanh_fast(acc[a][b]);

  float w1j[4], w2i[4];
  #pragma unroll
  for (int b = 0; b < 4; ++b)
    w1j[b] = WSCALE_ * __expf(cval[(size_t)b1 * HW_ + j0 + tj * 4 + b] - m1) * rl1;
  #pragma unroll
  for (int a = 0; a < 4; ++a)
    w2i[a] = WSCALE_ * __expf(cval[(size_t)b2 * HW_ + i0 + ti * 4 + a] - m2) * rl2;

  unsigned short* __restrict__ An  = Abf  + ((size_t)n << 20);
  unsigned short* __restrict__ Atn = Atbf + ((size_t)n << 20);
  #pragma unroll
  for (int a = 0; a < 4; ++a){
    ushort4 va;
    va.x = f2h(tf[a][0] * w1j[0]); va.y = f2h(tf[a][1] * w1j[1]);
    va.z = f2h(tf[a][2] * w1j[2]); va.w = f2h(tf[a][3] * w1j[3]);
    *(ushort4*)&An[(size_t)(i0 + ti * 4 + a) * HW_ + j0 + tj * 4] = va;
  }
  #pragma unroll
  for (int b = 0; b < 4; ++b){
    ushort4 vb;
    vb.x = f2h(tf[0][b] * w2i[0]); vb.y = f2h(tf[1][b] * w2i[1]);
    vb.z = f2h(tf[2][b] * w2i[2]); vb.w = f2h(tf[3][b] * w2i[3]);
    *(ushort4*)&at_s[tj * 4 + b][ti * 4] = vb;
  }
  __syncthreads();
  #pragma unroll
  for (int rep = 0; rep < 2; ++rep){
    const int idx = t + rep * 256;
    const int r = idx >> 3, q = (idx & 7) * 8;
    const ushort4 lo = *(const ushort4*)&at_s[r][q];
    const ushort4 hi = *(const ushort4*)&at_s[r][q + 4];
    *(ushort4*)&Atn[(size_t)(j0 + r) * HW_ + i0 + q] = lo;
    *(ushort4*)&Atn[(size_t)(j0 + r) * HW_ + i0 + q + 4] = hi;
  }
}

// K3: fused MFMA GEMM + L2-norm + resid/ReLU + next-iter sa-dot.
// 1024 threads = 16 waves (4 waves/SIMD): doubled intra-block TLP.
// BM=256 BN=64 BK=32, 3-deep counted-vmcnt pipeline, 60 KB LDS.
// Wave grid 4x4: wave tile 64 rows x 16 cols (acc = 4 frags).
__global__ __launch_bounds__(1024, 4) void k_gemm_fused(
    const _Float16* __restrict__ fhc1, const _Float16* __restrict__ fhc2,
    const unsigned short* __restrict__ Abf, const unsigned short* __restrict__ Atbf,
    const float* __restrict__ fpin1, const float* __restrict__ fpin2,
    float* __restrict__ fpo1, float* __restrict__ fpo2,
    _Float16* __restrict__ fhn1, _Float16* __restrict__ fhn2,
    const float* __restrict__ pw1, const float* __restrict__ pw2,
    const float* __restrict__ cw1, const float* __restrict__ cw2,
    float* __restrict__ cval, float* __restrict__ pdot,
    float* __restrict__ mpart, float* __restrict__ spart,
    float* __restrict__ out, int last)
{
  const int bid = blockIdx.x;
  const int n = bid & 7, r2 = bid >> 3;
  const int g = r2 >> 4, i0 = (r2 & 15) * 64;
  const unsigned short* __restrict__ X =
      (const unsigned short*)((g ? fhc2 : fhc1) + (size_t)n * C_ * HW_);
  const unsigned short* __restrict__ B = (g ? Atbf : Abf) + ((size_t)n << 20);

  __shared__ __align__(16) unsigned char pool[61440];  // 60 KB
  // loop:  Xs[buf] at buf*16384 (3x16KB); Bs[buf] at 49152 + buf*4096 (3x4KB)
  // epi :  pwT f32[256][20] @0; redp f32[16][17][16] @20480;
  //        ssred f32[4][64] @37888; rinv f32[64] @38912

  const int t = threadIdx.x, w = t >> 6, l = t & 63;
  const int wr = w >> 2, wc = w & 3;

  f32x4 acc[4];
  #pragma unroll
  for (int fm = 0; fm < 4; ++fm) acc[fm] = (f32x4){0.f, 0.f, 0.f, 0.f};

  // per wave per stage: 1 X chunk (+1 B chunk for waves 0..3)
  auto stage = [&](int buf, int k0){
    unsigned short* Xsb = (unsigned short*)(pool + buf * 16384);
    {
      const int q = w * 64 + l;           // 0..1023, covers all 1024 16B chunks
      const int row = q >> 2;
      const int kc = (q & 3) ^ (row & 3);
      GLD16(X + (size_t)row * HW_ + k0 + kc * 8, &Xsb[w * 512]);
    }
    if (w < 4){
      unsigned short* Bsb = (unsigned short*)(pool + 49152 + buf * 4096);
      const int q = w * 64 + l;           // 0..255
      const int row = q >> 2;
      const int kc = (q & 3) ^ (row & 3);
      GLD16(B + (size_t)(i0 + row) * HW_ + k0 + kc * 8, &Bsb[w * 512]);
    }
  };

  stage(0, 0);
  stage(1, 32);
  stage(2, 64);

  int cur = 0;
  for (int kt = 0; kt < 32; ++kt){
    const int rem = (31 - kt) < 2 ? (31 - kt) : 2;  // stages in flight after this wait
    if (w < 4){
      if (rem == 2)      WAITV(4);
      else if (rem == 1) WAITV(2);
      else               WAITV(0);
    } else {
      if (rem == 2)      WAITV(2);
      else if (rem == 1) WAITV(1);
      else               WAITV(0);
    }
    __builtin_amdgcn_sched_barrier(0);
    __builtin_amdgcn_s_barrier();

    const unsigned short* Xsb = (const unsigned short*)(pool + cur * 16384);
    const unsigned short* Bsb = (const unsigned short*)(pool + 49152 + cur * 4096);
    half8 a[4], bb;
    #pragma unroll
    for (int fm = 0; fm < 4; ++fm){
      const int row = wr * 64 + fm * 16 + (l & 15);
      const int kc = (l >> 4) ^ (row & 3);
      a[fm] = *(const half8*)&Xsb[row * 32 + kc * 8];
    }
    {
      const int row = wc * 16 + (l & 15);
      const int kc = (l >> 4) ^ (row & 3);
      bb = *(const half8*)&Bsb[row * 32 + kc * 8];
    }
    #pragma unroll
    for (int fm = 0; fm < 4; ++fm)
      acc[fm] = __builtin_amdgcn_mfma_f32_16x16x32_f16(a[fm], bb, acc[fm], 0, 0, 0);

    asm volatile("s_waitcnt lgkmcnt(0)" ::: "memory");
    __builtin_amdgcn_sched_barrier(0);
    __builtin_amdgcn_s_barrier();
    __builtin_amdgcn_sched_barrier(0);

    if (kt < 29) stage(cur, (kt + 3) * 32);
    cur = (cur == 2) ? 0 : cur + 1;
  }

  // ---- epilogue: L2-norm + resid/relu + next-iter sa-dot (or h output) ----
  float* pwT   = (float*)pool;             // [256][20]
  float* redp  = (float*)(pool + 20480);   // [16][17][16]
  float* ssred = (float*)(pool + 37888);   // [4][64]
  float* rinvp = (float*)(pool + 38912);   // [64]

  float ss = 0.f;
  #pragma unroll
  for (int fm = 0; fm < 4; ++fm)
    #pragma unroll
    for (int r = 0; r < 4; ++r) ss += acc[fm][r] * acc[fm][r];
  ss += __shfl_xor(ss, 16);
  ss += __shfl_xor(ss, 32);
  if (l < 16) ssred[wr * 64 + wc * 16 + l] = ss;

  if (!last){
    const float* __restrict__ pw = g ? pw2 : pw1;
    const float* __restrict__ cw = g ? cw2 : cw1;
    {
      const int idx = t * 4;                 // 1024 threads x 4 = 4096 pw entries
      const int lq = idx >> 8, c = idx & 255;
      const float4 p0 = *(const float4*)&pw[lq * C_ + c];
      pwT[(c + 0) * 20 + lq] = p0.x; pwT[(c + 1) * 20 + lq] = p0.y;
      pwT[(c + 2) * 20 + lq] = p0.z; pwT[(c + 3) * 20 + lq] = p0.w;
    }
    if (t < 64){
      const int c = t * 4;
      const float4 c0 = *(const float4*)&cw[c];
      pwT[(c + 0) * 20 + 16] = c0.x; pwT[(c + 1) * 20 + 16] = c0.y;
      pwT[(c + 2) * 20 + 16] = c0.z; pwT[(c + 3) * 20 + 16] = c0.w;
    }
  }
  __syncthreads();
  if (t < 64){
    const float s = ssred[t] + ssred[64 + t] + ssred[128 + t] + ssred[192 + t];
    rinvp[t] = 1.f / fmaxf(sqrtf(s), 1e-12f);
  }
  __syncthreads();
  const float ri = rinvp[wc * 16 + (l & 15)];

  const float* __restrict__ fpin = (g ? fpin2 : fpin1) + (size_t)n * C_ * HW_;
  float* __restrict__ fpo  = (g ? fpo2 : fpo1) + (size_t)n * C_ * HW_;
  _Float16* __restrict__ fhn = (g ? fhn2 : fhn1) + (size_t)n * C_ * HW_;
  float* __restrict__ outp = out + (size_t)g * SZ_ + (size_t)n * C_ * HW_;
  const int rbase = (l >> 4) * 4, col = l & 15;
  const int baseio = n * 2 + g;

  if (!last){
    float sacc[17];
    #pragma unroll
    for (int lq = 0; lq < 17; ++lq) sacc[lq] = 0.f;

    #pragma unroll
    for (int fm = 0; fm < 4; ++fm)
      #pragma unroll
      for (int r = 0; r < 4; ++r){
        const int c = wr * 64 + fm * 16 + rbase + r;
        float prow[17];
        #pragma unroll
        for (int q4 = 0; q4 < 4; ++q4){
          const float4 pv = *(const float4*)&pwT[c * 20 + q4 * 4];
          prow[q4 * 4 + 0] = pv.x; prow[q4 * 4 + 1] = pv.y;
          prow[q4 * 4 + 2] = pv.z; prow[q4 * 4 + 3] = pv.w;
        }
        prow[16] = pwT[c * 20 + 16];
        const size_t base = (size_t)c * HW_ + i0 + wc * 16 + col;
        const float h = acc[fm][r] * ri;
        const float fv = fpin[base] + h;
        const float rv = fv > 0.f ? fv : 0.f;
        fpo[base] = rv;
        fhn[base] = (_Float16)rv;
        #pragma unroll
        for (int lq = 0; lq < 17; ++lq) sacc[lq] += rv * prow[lq];
      }

    #pragma unroll
    for (int lq = 0; lq < 17; ++lq){
      float v = sacc[lq];
      v += __shfl_xor(v, 16);
      v += __shfl_xor(v, 32);
      sacc[lq] = v;
    }
    if (l < 16){
      #pragma unroll
      for (int lq = 0; lq < 17; ++lq)
        redp[((wr * 4 + wc) * 17 + lq) * 16 + l] = sacc[lq];
    }
    __syncthreads();
    if (t < 64){
      const int wcx = t >> 4, colx = t & 15;
      float xc = 0.f;
      #pragma unroll
      for (int lq = 0; lq < 17; ++lq){
        float s = 0.f;
        #pragma unroll
        for (int wrx = 0; wrx < 4; ++wrx)
          s += redp[((wrx * 4 + wcx) * 17 + lq) * 16 + colx];
        if (lq < 16) pdot[((size_t)baseio * CL_ + lq) * HW_ + i0 + t] = s;
        else       { cval[(size_t)baseio * HW_ + i0 + t] = s; xc = s; }
      }
      float mb = xc;
      #pragma unroll
      for (int off = 32; off; off >>= 1) mb = fmaxf(mb, __shfl_xor(mb, off));
      float e = __expf(xc - mb);
      #pragma unroll
      for (int off = 32; off; off >>= 1) e += __shfl_xor(e, off);
      if (t == 0){
        mpart[baseio * 16 + (i0 >> 6)] = mb;
        spart[baseio * 16 + (i0 >> 6)] = e;
      }
    }
  } else {
    #pragma unroll
    for (int fm = 0; fm < 4; ++fm){
      const size_t base = (size_t)(wr * 64 + fm * 16 + rbase) * HW_ + i0 + wc * 16 + col;
      #pragma unroll
      for (int r = 0; r < 4; ++r)
        outp[base + (size_t)r * HW_] = acc[fm][r] * ri;
    }
  }
}

// K_s: s[n,c,hw] = w * fp (fp32 state),  w = exp(cval - m) * rl
__global__ __launch_bounds__(256) void k_s_out(
    const float* __restrict__ fp1, const float* __restrict__ fp2,
    const float* __restrict__ cval,
    const float* __restrict__ mpart, const float* __restrict__ spart,
    float* __restrict__ out)
{
  const int side = blockIdx.y;
  const size_t fo = ((size_t)blockIdx.x * 256 + threadIdx.x) * 4;
  const float* __restrict__ f = side ? fp2 : fp1;
  const int n  = (int)(fo >> 18);
  const int hw = (int)(fo & (HW_ - 1));
  const int base = n * 2 + side;
  float m, rl;
  combine16(mpart, spart, base, m, rl);
  const float4 c = *(const float4*)&cval[(size_t)base * HW_ + hw];
  const float4 v = *(const float4*)&f[fo];
  float4 r;
  r.x = v.x * (__expf(c.x - m) * rl);
  r.y = v.y * (__expf(c.y - m) * rl);
  r.z = v.z * (__expf(c.z - m) * rl);
  r.w = v.w * (__expf(c.w - m) * rl);
  *(float4*)&out[(size_t)(2 + side) * SZ_ + fo] = r;
}

extern "C" void kernel_launch(void* const* d_in, const int* in_sizes, int n_in,
                              void* d_out, int out_size, void* d_ws, size_t ws_size,
                              hipStream_t stream)
{
  const float* f1  = (const float*)d_in[0];
  const float* f2  = (const float*)d_in[1];
  const float* pw1 = (const float*)d_in[2];
  const float* pb1 = (const float*)d_in[3];
  const float* pw2 = (const float*)d_in[4];
  const float* pb2 = (const float*)d_in[5];
  const float* cw1 = (const float*)d_in[6];
  const float* cw2 = (const float*)d_in[8];
  // cb1/cb2 unused: softmax is shift-invariant
  float* out = (float*)d_out;
  float* ws  = (float*)d_ws;

  float* cval  = ws;                           // 16K f32
  float* pdot  = cval + N_ * 2 * HW_;          // 256K f32
  float* mpart = pdot + N_ * 2 * CL_ * HW_;    // 512
  float* spart = mpart + 512;                  // 512
  float* fp1   = spart + 512;                  // SZ_ f32 state
  float* fp2   = fp1 + SZ_;                    // SZ_ f32 state
  _Float16* fhA1 = (_Float16*)(fp2 + SZ_);     // SZ_ fp16 mirror (ping)
  _Float16* fhA2 = fhA1 + SZ_;
  _Float16* fhB1 = fhA2 + SZ_;                 // SZ_ fp16 mirror (pong)
  _Float16* fhB2 = fhB1 + SZ_;
  unsigned short* Abf  = (unsigned short*)(fhB2 + SZ_);  // 8M fp16
  unsigned short* Atbf = Abf + ((size_t)N_ << 20);       // 8M fp16

  k_sa_dot<<<dim3(256), 256, 0, stream>>>(f1, f2, cw1, cw2, pw1, pw2,
                                          cval, pdot, mpart, spart, fhA1, fhA2);

  for (int it = 0; it < 5; ++it){
    const float* cur1 = (it == 0) ? f1 : fp1;
    const float* cur2 = (it == 0) ? f2 : fp2;
    const _Float16* fhc1 = (it & 1) ? fhB1 : fhA1;
    const _Float16* fhc2 = (it & 1) ? fhB2 : fhA2;
    _Float16* fhn1 = (it & 1) ? fhA1 : fhB1;
    _Float16* fhn2 = (it & 1) ? fhA2 : fhB2;

    k_corr<<<dim3(2048), 256, 0, stream>>>(cval, pdot, pb1, pb2, mpart, spart, Abf, Atbf);
    if (it == 4)
      k_s_out<<<dim3(SZ_ / 4 / 256, 2), 256, 0, stream>>>(cur1, cur2, cval, mpart, spart, out);
    k_gemm_fused<<<dim3(256), 1024, 0, stream>>>(fhc1, fhc2, Abf, Atbf,
                                                 cur1, cur2, fp1, fp2, fhn1, fhn2,
                                                 pw1, pw2, cw1, cw2,
                                                 cval, pdot, mpart, spart,
                                                 out, (it == 4) ? 1 : 0);
  }
}

// Round 18
// 236.362 us; speedup vs baseline: 1.2140x; 1.0636x over previous
//
#include <hip/hip_runtime.h>
#include <cstdint>
#include <cstddef>

#define N_  8
#define C_  256
#define HW_ 1024
#define CL_ 16
#define SZ_ (N_*C_*HW_)   // 2,097,152 elements per tensor
#define WSCALE_ 4096.0f   // 2^12 exact; folded into A, cancels in L2-norm

typedef __attribute__((ext_vector_type(8))) _Float16 half8;
typedef __attribute__((ext_vector_type(4))) float f32x4;

static __device__ __forceinline__ float tanh_fast(float x){
  x = fminf(fmaxf(x, -15.f), 15.f);
  float e = __expf(2.f * x);
  return (e - 1.f) / (e + 1.f);
}

static __device__ __forceinline__ unsigned short f2h(float x){
  _Float16 h = (_Float16)x;
  return *(unsigned short*)&h;
}

// combine 16 online-softmax partials -> (m, 1/sumexp)
static __device__ __forceinline__ void combine16(
    const float* __restrict__ mpart, const float* __restrict__ spart,
    int base, float& m, float& rl)
{
  m = -1e30f;
  #pragma unroll
  for (int k = 0; k < 16; ++k) m = fmaxf(m, mpart[base * 16 + k]);
  float s = 0.f;
  #pragma unroll
  for (int k = 0; k < 16; ++k) s += spart[base * 16 + k] * __expf(mpart[base * 16 + k] - m);
  rl = 1.f / s;
}

#define GLD16(g, l) __builtin_amdgcn_global_load_lds( \
    (const __attribute__((address_space(1))) void*)(g), \
    (__attribute__((address_space(3))) void*)(l), 16, 0, 0)

#define WAITV(N) asm volatile("s_waitcnt vmcnt(" #N ")" ::: "memory")

// K1 (once): sa-dot on original fp32 inputs + fp16 mirror write.
// XCD affinity: 1D grid, n = bid & 7 -> all batch-n work on XCD n.
__global__ __launch_bounds__(256) void k_sa_dot(
    const float* __restrict__ fp1, const float* __restrict__ fp2,
    const float* __restrict__ cw1, const float* __restrict__ cw2,
    const float* __restrict__ pw1, const float* __restrict__ pw2,
    float* __restrict__ cval, float* __restrict__ pdot,
    float* __restrict__ mpart, float* __restrict__ spart,
    _Float16* __restrict__ fh1, _Float16* __restrict__ fh2)
{
  const int bid = blockIdx.x;
  const int n = bid & 7, r = bid >> 3;
  const int side = r >> 4, hw0 = (r & 15) * 64;
  const int t = threadIdx.x, hwl = t & 63, cg = t >> 6;
  const float* __restrict__ pw = side ? pw2 : pw1;
  const float* __restrict__ cw = side ? cw2 : cw1;
  const float* __restrict__ f  = (side ? fp2 : fp1) + (size_t)n * C_ * HW_ + hw0 + hwl;
  _Float16* __restrict__ fh = (side ? fh2 : fh1) + (size_t)n * C_ * HW_ + hw0 + hwl;
  const int cb = __builtin_amdgcn_readfirstlane(cg * 64);

  float acc[17];
  #pragma unroll
  for (int l = 0; l < 17; ++l) acc[l] = 0.f;

  for (int cc = 0; cc < 64; ++cc){
    const int c = cb + cc;
    const float v = f[(size_t)c * HW_];
    fh[(size_t)c * HW_] = (_Float16)v;
    acc[16] += v * cw[c];
    #pragma unroll
    for (int l = 0; l < 16; ++l) acc[l] += v * pw[l * C_ + c];
  }

  __shared__ float red[17][4][64];
  #pragma unroll
  for (int l = 0; l < 17; ++l) red[l][cg][hwl] = acc[l];
  __syncthreads();

  if (t < 64){
    const int base = n * 2 + side;
    float xc = 0.f;
    #pragma unroll
    for (int l = 0; l < 17; ++l){
      const float s = red[l][0][t] + red[l][1][t] + red[l][2][t] + red[l][3][t];
      if (l < 16) pdot[((size_t)base * CL_ + l) * HW_ + hw0 + t] = s;
      else      { cval[(size_t)base * HW_ + hw0 + t] = s; xc = s; }
    }
    float mb = xc;
    #pragma unroll
    for (int off = 32; off; off >>= 1) mb = fmaxf(mb, __shfl_xor(mb, off));
    float e = __expf(xc - mb);
    #pragma unroll
    for (int off = 32; off; off >>= 1) e += __shfl_xor(e, off);
    if (t == 0){
      mpart[base * 16 + (hw0 >> 6)] = mb;
      spart[base * 16 + (hw0 >> 6)] = e;
    }
  }
}

// K2: corr -> scaled-w-folded fp16 A / At (XCD-affine n = bid & 7)
__global__ __launch_bounds__(256) void k_corr(
    const float* __restrict__ cval, const float* __restrict__ pdot,
    const float* __restrict__ pb1, const float* __restrict__ pb2,
    const float* __restrict__ mpart, const float* __restrict__ spart,
    unsigned short* __restrict__ Abf, unsigned short* __restrict__ Atbf)
{
  const int bid = blockIdx.x;
  const int n = bid & 7, r4i = bid >> 3;
  const int i0 = (r4i >> 4) * 64, j0 = (r4i & 15) * 64;
  const int b1 = n * 2, b2 = n * 2 + 1;
  __align__(16) __shared__ float s2[CL_][64];
  __align__(16) __shared__ float s1[CL_][64];
  __shared__ unsigned short at_s[64][68];
  const int t = threadIdx.x;
  const int lr = t >> 4, lc = (t & 15) * 4;

  float m1, rl1, m2, rl2;
  combine16(mpart, spart, b1, m1, rl1);
  combine16(mpart, spart, b2, m2, rl2);

  {
    const float bias2 = pb2[lr];
    const float4 c2 = *(const float4*)&cval[(size_t)b2 * HW_ + i0 + lc];
    const float4 p2 = *(const float4*)&pdot[((size_t)b2 * CL_ + lr) * HW_ + i0 + lc];
    s2[lr][lc + 0] = __expf(c2.x - m2) * rl2 * p2.x + bias2;
    s2[lr][lc + 1] = __expf(c2.y - m2) * rl2 * p2.y + bias2;
    s2[lr][lc + 2] = __expf(c2.z - m2) * rl2 * p2.z + bias2;
    s2[lr][lc + 3] = __expf(c2.w - m2) * rl2 * p2.w + bias2;

    const float bias1 = pb1[lr];
    const float4 c1 = *(const float4*)&cval[(size_t)b1 * HW_ + j0 + lc];
    const float4 p1 = *(const float4*)&pdot[((size_t)b1 * CL_ + lr) * HW_ + j0 + lc];
    s1[lr][lc + 0] = __expf(c1.x - m1) * rl1 * p1.x + bias1;
    s1[lr][lc + 1] = __expf(c1.y - m1) * rl1 * p1.y + bias1;
    s1[lr][lc + 2] = __expf(c1.z - m1) * rl1 * p1.z + bias1;
    s1[lr][lc + 3] = __expf(c1.w - m1) * rl1 * p1.w + bias1;
  }
  __syncthreads();

  const int ti = t >> 4, tj = t & 15;
  float acc[4][4];
  #pragma unroll
  for (int a = 0; a < 4; ++a)
    #pragma unroll
    for (int b = 0; b < 4; ++b) acc[a][b] = 0.f;

  #pragma unroll
  for (int l = 0; l < CL_; ++l){
    const float4 a4 = *(const float4*)&s2[l][ti * 4];
    const float4 b4 = *(const float4*)&s1[l][tj * 4];
    const float av[4] = {a4.x, a4.y, a4.z, a4.w};
    const float bv[4] = {b4.x, b4.y, b4.z, b4.w};
    #pragma unroll
    for (int a = 0; a < 4; ++a)
      #pragma unroll
      for (int b = 0; b < 4; ++b) acc[a][b] += av[a] * bv[b];
  }

  float tf[4][4];
  #pragma unroll
  for (int a = 0; a < 4; ++a)
    #pragma unroll
    for (int b = 0; b < 4; ++b) tf[a][b] = tanh_fast(acc[a][b]);

  float w1j[4], w2i[4];
  #pragma unroll
  for (int b = 0; b < 4; ++b)
    w1j[b] = WSCALE_ * __expf(cval[(size_t)b1 * HW_ + j0 + tj * 4 + b] - m1) * rl1;
  #pragma unroll
  for (int a = 0; a < 4; ++a)
    w2i[a] = WSCALE_ * __expf(cval[(size_t)b2 * HW_ + i0 + ti * 4 + a] - m2) * rl2;

  unsigned short* __restrict__ An  = Abf  + ((size_t)n << 20);
  unsigned short* __restrict__ Atn = Atbf + ((size_t)n << 20);
  #pragma unroll
  for (int a = 0; a < 4; ++a){
    ushort4 va;
    va.x = f2h(tf[a][0] * w1j[0]); va.y = f2h(tf[a][1] * w1j[1]);
    va.z = f2h(tf[a][2] * w1j[2]); va.w = f2h(tf[a][3] * w1j[3]);
    *(ushort4*)&An[(size_t)(i0 + ti * 4 + a) * HW_ + j0 + tj * 4] = va;
  }
  #pragma unroll
  for (int b = 0; b < 4; ++b){
    ushort4 vb;
    vb.x = f2h(tf[0][b] * w2i[0]); vb.y = f2h(tf[1][b] * w2i[1]);
    vb.z = f2h(tf[2][b] * w2i[2]); vb.w = f2h(tf[3][b] * w2i[3]);
    *(ushort4*)&at_s[tj * 4 + b][ti * 4] = vb;
  }
  __syncthreads();
  #pragma unroll
  for (int rep = 0; rep < 2; ++rep){
    const int idx = t + rep * 256;
    const int r = idx >> 3, q = (idx & 7) * 8;
    const ushort4 lo = *(const ushort4*)&at_s[r][q];
    const ushort4 hi = *(const ushort4*)&at_s[r][q + 4];
    *(ushort4*)&Atn[(size_t)(j0 + r) * HW_ + i0 + q] = lo;
    *(ushort4*)&Atn[(size_t)(j0 + r) * HW_ + i0 + q + 4] = hi;
  }
}

// K3: fused MFMA GEMM + L2-norm + resid/ReLU + next-iter sa-dot.
// BM=256 BN=64 BK=32, 3-deep counted-vmcnt pipeline, XCD-affine (n = bid & 7).
__global__ __launch_bounds__(512, 4) void k_gemm_fused(
    const _Float16* __restrict__ fhc1, const _Float16* __restrict__ fhc2,
    const unsigned short* __restrict__ Abf, const unsigned short* __restrict__ Atbf,
    const float* __restrict__ fpin1, const float* __restrict__ fpin2,
    float* __restrict__ fpo1, float* __restrict__ fpo2,
    _Float16* __restrict__ fhn1, _Float16* __restrict__ fhn2,
    const float* __restrict__ pw1, const float* __restrict__ pw2,
    const float* __restrict__ cw1, const float* __restrict__ cw2,
    float* __restrict__ cval, float* __restrict__ pdot,
    float* __restrict__ mpart, float* __restrict__ spart,
    float* __restrict__ out, int last)
{
  const int bid = blockIdx.x;
  const int n = bid & 7, r2 = bid >> 3;
  const int g = r2 >> 4, i0 = (r2 & 15) * 64;
  const unsigned short* __restrict__ X =
      (const unsigned short*)((g ? fhc2 : fhc1) + (size_t)n * C_ * HW_);
  const unsigned short* __restrict__ B = (g ? Atbf : Abf) + ((size_t)n << 20);

  __shared__ __align__(16) unsigned char pool[61440];  // 60 KB
  // loop:  Xs[buf] at buf*16384 (3x16KB); Bs[buf] at 49152 + buf*4096 (3x4KB)
  // epi :  pwT f32[256][20] @0; redp f32[4][2][2][17][16] @20480;
  //        ssred f32[4][64] @55296; rinv f32[64] @56320

  const int t = threadIdx.x, w = t >> 6, l = t & 63;
  const int wr = w >> 1, wc = w & 1;

  f32x4 acc[4][2];
  #pragma unroll
  for (int fm = 0; fm < 4; ++fm)
    #pragma unroll
    for (int fn = 0; fn < 2; ++fn)
      acc[fm][fn] = (f32x4){0.f, 0.f, 0.f, 0.f};

  // per wave per stage: 2 X loads (+1 B load for waves 0..3)
  auto stage = [&](int buf, int k0){
    unsigned short* Xsb = (unsigned short*)(pool + buf * 16384);
    #pragma unroll
    for (int s = 0; s < 2; ++s){
      const int q = (w * 2 + s) * 64 + l;
      const int row = q >> 2;
      const int kc = (q & 3) ^ (row & 3);
      GLD16(X + (size_t)row * HW_ + k0 + kc * 8, &Xsb[(w * 2 + s) * 512]);
    }
    if (w < 4){
      unsigned short* Bsb = (unsigned short*)(pool + 49152 + buf * 4096);
      const int q = w * 64 + l;
      const int row = q >> 2;
      const int kc = (q & 3) ^ (row & 3);
      GLD16(B + (size_t)(i0 + row) * HW_ + k0 + kc * 8, &Bsb[w * 512]);
    }
  };

  stage(0, 0);
  stage(1, 32);
  stage(2, 64);

  int cur = 0;
  for (int kt = 0; kt < 32; ++kt){
    const int rem = (31 - kt) < 2 ? (31 - kt) : 2;  // stages still in flight after wait
    if (w < 4){
      if (rem == 2)      WAITV(6);
      else if (rem == 1) WAITV(3);
      else               WAITV(0);
    } else {
      if (rem == 2)      WAITV(4);
      else if (rem == 1) WAITV(2);
      else               WAITV(0);
    }
    __builtin_amdgcn_sched_barrier(0);
    __builtin_amdgcn_s_barrier();

    const unsigned short* Xsb = (const unsigned short*)(pool + cur * 16384);
    const unsigned short* Bsb = (const unsigned short*)(pool + 49152 + cur * 4096);
    half8 a[4], bb[2];
    #pragma unroll
    for (int fm = 0; fm < 4; ++fm){
      const int row = wr * 64 + fm * 16 + (l & 15);
      const int kc = (l >> 4) ^ (row & 3);
      a[fm] = *(const half8*)&Xsb[row * 32 + kc * 8];
    }
    #pragma unroll
    for (int fn = 0; fn < 2; ++fn){
      const int row = wc * 32 + fn * 16 + (l & 15);
      const int kc = (l >> 4) ^ (row & 3);
      bb[fn] = *(const half8*)&Bsb[row * 32 + kc * 8];
    }
    #pragma unroll
    for (int fm = 0; fm < 4; ++fm)
      #pragma unroll
      for (int fn = 0; fn < 2; ++fn)
        acc[fm][fn] = __builtin_amdgcn_mfma_f32_16x16x32_f16(a[fm], bb[fn], acc[fm][fn], 0, 0, 0);

    asm volatile("s_waitcnt lgkmcnt(0)" ::: "memory");
    __builtin_amdgcn_sched_barrier(0);
    __builtin_amdgcn_s_barrier();
    __builtin_amdgcn_sched_barrier(0);

    if (kt < 29) stage(cur, (kt + 3) * 32);
    cur = (cur == 2) ? 0 : cur + 1;
  }

  // ---- epilogue: L2-norm + resid/relu + next-iter sa-dot (or h output) ----
  float* pwT   = (float*)pool;             // [256][20]
  float* redp  = (float*)(pool + 20480);   // [4][2][2][17][16]
  float* ssred = (float*)(pool + 55296);   // [4][64]
  float* rinvp = (float*)(pool + 56320);   // [64]

  float ss0 = 0.f, ss1 = 0.f;
  #pragma unroll
  for (int fm = 0; fm < 4; ++fm)
    #pragma unroll
    for (int r = 0; r < 4; ++r){
      ss0 += acc[fm][0][r] * acc[fm][0][r];
      ss1 += acc[fm][1][r] * acc[fm][1][r];
    }
  ss0 += __shfl_xor(ss0, 16); ss0 += __shfl_xor(ss0, 32);
  ss1 += __shfl_xor(ss1, 16); ss1 += __shfl_xor(ss1, 32);
  if (l < 16){
    ssred[wr * 64 + wc * 32 + l]      = ss0;
    ssred[wr * 64 + wc * 32 + 16 + l] = ss1;
  }

  if (!last){
    const float* __restrict__ pw = g ? pw2 : pw1;
    const float* __restrict__ cw = g ? cw2 : cw1;
    {
      const int idx = t * 8;
      const int lq = idx >> 8, c = idx & 255;
      const float4 p0 = *(const float4*)&pw[lq * C_ + c];
      const float4 p1 = *(const float4*)&pw[lq * C_ + c + 4];
      pwT[(c + 0) * 20 + lq] = p0.x; pwT[(c + 1) * 20 + lq] = p0.y;
      pwT[(c + 2) * 20 + lq] = p0.z; pwT[(c + 3) * 20 + lq] = p0.w;
      pwT[(c + 4) * 20 + lq] = p1.x; pwT[(c + 5) * 20 + lq] = p1.y;
      pwT[(c + 6) * 20 + lq] = p1.z; pwT[(c + 7) * 20 + lq] = p1.w;
    }
    if (t < 32){
      const float4 c0 = *(const float4*)&cw[t * 8];
      const float4 c1 = *(const float4*)&cw[t * 8 + 4];
      pwT[(t * 8 + 0) * 20 + 16] = c0.x; pwT[(t * 8 + 1) * 20 + 16] = c0.y;
      pwT[(t * 8 + 2) * 20 + 16] = c0.z; pwT[(t * 8 + 3) * 20 + 16] = c0.w;
      pwT[(t * 8 + 4) * 20 + 16] = c1.x; pwT[(t * 8 + 5) * 20 + 16] = c1.y;
      pwT[(t * 8 + 6) * 20 + 16] = c1.z; pwT[(t * 8 + 7) * 20 + 16] = c1.w;
    }
  }
  __syncthreads();
  if (t < 64){
    const float s = ssred[t] + ssred[64 + t] + ssred[128 + t] + ssred[192 + t];
    rinvp[t] = 1.f / fmaxf(sqrtf(s), 1e-12f);
  }
  __syncthreads();
  const float ri[2] = { rinvp[wc * 32 + (l & 15)], rinvp[wc * 32 + 16 + (l & 15)] };

  const float* __restrict__ fpin = (g ? fpin2 : fpin1) + (size_t)n * C_ * HW_;
  float* __restrict__ fpo  = (g ? fpo2 : fpo1) + (size_t)n * C_ * HW_;
  _Float16* __restrict__ fhn = (g ? fhn2 : fhn1) + (size_t)n * C_ * HW_;
  float* __restrict__ outp = out + (size_t)g * SZ_ + (size_t)n * C_ * HW_;
  const int rbase = (l >> 4) * 4, col = l & 15;
  const int baseio = n * 2 + g;

  if (!last){
    float sacc[2][17];
    #pragma unroll
    for (int fn = 0; fn < 2; ++fn)
      #pragma unroll
      for (int lq = 0; lq < 17; ++lq) sacc[fn][lq] = 0.f;

    #pragma unroll
    for (int fm = 0; fm < 4; ++fm)
      #pragma unroll
      for (int r = 0; r < 4; ++r){
        const int c = wr * 64 + fm * 16 + rbase + r;
        float prow[17];
        #pragma unroll
        for (int q4 = 0; q4 < 4; ++q4){
          const float4 pv = *(const float4*)&pwT[c * 20 + q4 * 4];
          prow[q4 * 4 + 0] = pv.x; prow[q4 * 4 + 1] = pv.y;
          prow[q4 * 4 + 2] = pv.z; prow[q4 * 4 + 3] = pv.w;
        }
        prow[16] = pwT[c * 20 + 16];
        #pragma unroll
        for (int fn = 0; fn < 2; ++fn){
          const size_t base = (size_t)c * HW_ + i0 + wc * 32 + fn * 16 + col;
          const float h = acc[fm][fn][r] * ri[fn];
          const float fv = fpin[base] + h;
          const float rv = fv > 0.f ? fv : 0.f;
          fpo[base] = rv;
          fhn[base] = (_Float16)rv;
          #pragma unroll
          for (int lq = 0; lq < 17; ++lq) sacc[fn][lq] += rv * prow[lq];
        }
      }

    #pragma unroll
    for (int fn = 0; fn < 2; ++fn)
      #pragma unroll
      for (int lq = 0; lq < 17; ++lq){
        float v = sacc[fn][lq];
        v += __shfl_xor(v, 16);
        v += __shfl_xor(v, 32);
        sacc[fn][lq] = v;
      }
    if (l < 16){
      #pragma unroll
      for (int fn = 0; fn < 2; ++fn)
        #pragma unroll
        for (int lq = 0; lq < 17; ++lq)
          redp[(((wr * 2 + wc) * 2 + fn) * 17 + lq) * 16 + l] = sacc[fn][lq];
    }
    __syncthreads();
    if (t < 64){
      const int wcx = t >> 5, fnx = (t >> 4) & 1, colx = t & 15;
      float xc = 0.f;
      #pragma unroll
      for (int lq = 0; lq < 17; ++lq){
        float s = 0.f;
        #pragma unroll
        for (int wrx = 0; wrx < 4; ++wrx)
          s += redp[(((wrx * 2 + wcx) * 2 + fnx) * 17 + lq) * 16 + colx];
        if (lq < 16) pdot[((size_t)baseio * CL_ + lq) * HW_ + i0 + t] = s;
        else       { cval[(size_t)baseio * HW_ + i0 + t] = s; xc = s; }
      }
      float mb = xc;
      #pragma unroll
      for (int off = 32; off; off >>= 1) mb = fmaxf(mb, __shfl_xor(mb, off));
      float e = __expf(xc - mb);
      #pragma unroll
      for (int off = 32; off; off >>= 1) e += __shfl_xor(e, off);
      if (t == 0){
        mpart[baseio * 16 + (i0 >> 6)] = mb;
        spart[baseio * 16 + (i0 >> 6)] = e;
      }
    }
  } else {
    #pragma unroll
    for (int fm = 0; fm < 4; ++fm)
      #pragma unroll
      for (int fn = 0; fn < 2; ++fn){
        const size_t base = (size_t)(wr * 64 + fm * 16 + rbase) * HW_ + i0 + wc * 32 + fn * 16 + col;
        #pragma unroll
        for (int r = 0; r < 4; ++r)
          outp[base + (size_t)r * HW_] = acc[fm][fn][r] * ri[fn];
      }
  }
}

// K_s: s[n,c,hw] = w * fp (fp32 state),  w = exp(cval - m) * rl
__global__ __launch_bounds__(256) void k_s_out(
    const float* __restrict__ fp1, const float* __restrict__ fp2,
    const float* __restrict__ cval,
    const float* __restrict__ mpart, const float* __restrict__ spart,
    float* __restrict__ out)
{
  const int side = blockIdx.y;
  const size_t fo = ((size_t)blockIdx.x * 256 + threadIdx.x) * 4;
  const float* __restrict__ f = side ? fp2 : fp1;
  const int n  = (int)(fo >> 18);
  const int hw = (int)(fo & (HW_ - 1));
  const int base = n * 2 + side;
  float m, rl;
  combine16(mpart, spart, base, m, rl);
  const float4 c = *(const float4*)&cval[(size_t)base * HW_ + hw];
  const float4 v = *(const float4*)&f[fo];
  float4 r;
  r.x = v.x * (__expf(c.x - m) * rl);
  r.y = v.y * (__expf(c.y - m) * rl);
  r.z = v.z * (__expf(c.z - m) * rl);
  r.w = v.w * (__expf(c.w - m) * rl);
  *(float4*)&out[(size_t)(2 + side) * SZ_ + fo] = r;
}

extern "C" void kernel_launch(void* const* d_in, const int* in_sizes, int n_in,
                              void* d_out, int out_size, void* d_ws, size_t ws_size,
                              hipStream_t stream)
{
  const float* f1  = (const float*)d_in[0];
  const float* f2  = (const float*)d_in[1];
  const float* pw1 = (const float*)d_in[2];
  const float* pb1 = (const float*)d_in[3];
  const float* pw2 = (const float*)d_in[4];
  const float* pb2 = (const float*)d_in[5];
  const float* cw1 = (const float*)d_in[6];
  const float* cw2 = (const float*)d_in[8];
  // cb1/cb2 unused: softmax is shift-invariant
  float* out = (float*)d_out;
  float* ws  = (float*)d_ws;

  float* cval  = ws;                           // 16K f32
  float* pdot  = cval + N_ * 2 * HW_;          // 256K f32
  float* mpart = pdot + N_ * 2 * CL_ * HW_;    // 512
  float* spart = mpart + 512;                  // 512
  float* fp1   = spart + 512;                  // SZ_ f32 state
  float* fp2   = fp1 + SZ_;                    // SZ_ f32 state
  _Float16* fhA1 = (_Float16*)(fp2 + SZ_);     // SZ_ fp16 mirror (ping)
  _Float16* fhA2 = fhA1 + SZ_;
  _Float16* fhB1 = fhA2 + SZ_;                 // SZ_ fp16 mirror (pong)
  _Float16* fhB2 = fhB1 + SZ_;
  unsigned short* Abf  = (unsigned short*)(fhB2 + SZ_);  // 8M fp16
  unsigned short* Atbf = Abf + ((size_t)N_ << 20);       // 8M fp16

  k_sa_dot<<<dim3(256), 256, 0, stream>>>(f1, f2, cw1, cw2, pw1, pw2,
                                          cval, pdot, mpart, spart, fhA1, fhA2);

  for (int it = 0; it < 5; ++it){
    const float* cur1 = (it == 0) ? f1 : fp1;
    const float* cur2 = (it == 0) ? f2 : fp2;
    const _Float16* fhc1 = (it & 1) ? fhB1 : fhA1;
    const _Float16* fhc2 = (it & 1) ? fhB2 : fhA2;
    _Float16* fhn1 = (it & 1) ? fhA1 : fhB1;
    _Float16* fhn2 = (it & 1) ? fhA2 : fhB2;

    k_corr<<<dim3(2048), 256, 0, stream>>>(cval, pdot, pb1, pb2, mpart, spart, Abf, Atbf);
    if (it == 4)
      k_s_out<<<dim3(SZ_ / 4 / 256, 2), 256, 0, stream>>>(cur1, cur2, cval, mpart, spart, out);
    k_gemm_fused<<<dim3(256), 512, 0, stream>>>(fhc1, fhc2, Abf, Atbf,
                                                cur1, cur2, fp1, fp2, fhn1, fhn2,
                                                pw1, pw2, cw1, cw2,
                                                cval, pdot, mpart, spart,
                                                out, (it == 4) ? 1 : 0);
  }
}